// Round 6
// baseline (196839.685 us; speedup 1.0000x reference)
//
#include <hip/hip_runtime.h>
#include <math.h>

#define SEQ   8192
#define NIN   256
#define H     2048
#define NBLK  256
#define NTHR  256

typedef unsigned long long u64;

// ---- ws layout: u64 recs[rot][NBLK][8] ----
// Element e of record (slot,b) = { hi32: step tag, lo32: f32 bits of h[8b+e] }.
// Self-validating: each 8B word carries its own epoch. Harness poison
// 0xAAAAAAAA can never equal a valid tag (0..8192), so only slot 0 needs init.
__global__ void lstm_init(const float* __restrict__ h0, u64* __restrict__ recs)
{
    const int j = threadIdx.x;   // one block of 256: record j of slot 0, tag 0
    #pragma unroll
    for (int e = 0; e < 8; ++e)
        recs[8 * j + e] = (u64)__builtin_bit_cast(unsigned, h0[8 * j + e]);
}

// Persistent LSTM. fp32 weights register-resident, fp64 recurrence math,
// fp32 h transport via epoch-tagged u64 records with slot rotation.
// Fast path: plain cached loads (L2 multicast per XCD); tag mismatch -> sc1 spin.
__global__ void __launch_bounds__(NTHR, 1)
lstm_persist(const float* __restrict__ x, const float* __restrict__ c0,
             const float* __restrict__ w_ih, const float* __restrict__ w_hh,
             const float* __restrict__ b_ih, const float* __restrict__ b_hh,
             const float* __restrict__ w_lin, const float* __restrict__ b_lin,
             float* __restrict__ out, u64* __restrict__ recs, int rot_mask)
{
    const int b = blockIdx.x, tid = threadIdx.x;
    const int wv = tid >> 6, ln = tid & 63;

    __shared__ float  h_lds[H + H / 32];   // stride-33: 2-way bank alias = free
    __shared__ double gsum[4][8];
    __shared__ double bias_s[4][8];
    __shared__ double red0[4], red1[4];

    if (tid < 32) {
        int g = tid >> 3, r = tid & 7;
        int R = g * H + b * 8 + r;
        bias_s[g][r] = (double)b_ih[R] + (double)b_hh[R];
    }
    double c_reg = (wv == 0 && ln < 8) ? (double)c0[b * 8 + ln] : 0.0;

    float wreg[8][32];
    float wih[8][4];
    #pragma unroll
    for (int r = 0; r < 8; ++r) {
        const int R = wv * H + b * 8 + r;
        const float4* wp = (const float4*)(w_hh + (size_t)R * H + ln * 32);
        #pragma unroll
        for (int q = 0; q < 8; ++q) ((float4*)wreg[r])[q] = wp[q];
        *(float4*)wih[r] = *(const float4*)(w_ih + (size_t)R * NIN + ln * 4);
    }
    __syncthreads();

    float4 xr = *(const float4*)(x + ln * 4);
    float4 xn = xr;

    for (int t = 0; t < SEQ; ++t) {
        // ---- consume: thread tid owns record tid -> h[8*tid .. 8*tid+8) ----
        {
            const u64* rec = recs + (((size_t)(t & rot_mask) * NBLK + tid) << 3);
            float hv[8];
            #pragma unroll
            for (int e = 0; e < 8; ++e) {
                // fast probe: plain cached load (workgroup scope == no sc bits)
                u64 v = __hip_atomic_load(rec + e, __ATOMIC_RELAXED,
                                          __HIP_MEMORY_SCOPE_WORKGROUP);
                while ((unsigned)(v >> 32) != (unsigned)t) {
                    __builtin_amdgcn_s_sleep(4);
                    v = __hip_atomic_load(rec + e, __ATOMIC_RELAXED,
                                          __HIP_MEMORY_SCOPE_AGENT);
                }
                hv[e] = __builtin_bit_cast(float, (unsigned)v);
            }
            const int base = 8 * tid + (tid >> 2);
            #pragma unroll
            for (int e = 0; e < 8; ++e) h_lds[base + e] = hv[e];
        }
        __syncthreads();   // #1: full h of step t in LDS

        if (t + 1 < SEQ) xn = *(const float4*)(x + (size_t)(t + 1) * NIN + ln * 4);

        // ---- matvec: fp32 w x fp32 h, fp64 accumulate ----
        float hbuf[32];
        {
            const float* hp = &h_lds[33 * ln];
            #pragma unroll
            for (int q = 0; q < 32; ++q) hbuf[q] = hp[q];
        }
        double acc[8];
        #pragma unroll
        for (int r = 0; r < 8; ++r)
            acc[r] = (double)wih[r][0] * (double)xr.x + (double)wih[r][1] * (double)xr.y
                   + (double)wih[r][2] * (double)xr.z + (double)wih[r][3] * (double)xr.w;
        #pragma unroll
        for (int q = 0; q < 32; ++q) {
            const double hq = (double)hbuf[q];
            #pragma unroll
            for (int r = 0; r < 8; ++r)
                acc[r] = fma((double)wreg[r][q], hq, acc[r]);
        }
        #pragma unroll
        for (int off = 32; off >= 1; off >>= 1) {
            #pragma unroll
            for (int r = 0; r < 8; ++r) acc[r] += __shfl_xor(acc[r], off, 64);
        }
        if (ln == 0) {
            #pragma unroll
            for (int r = 0; r < 8; ++r) gsum[wv][r] = acc[r];
        }
        __syncthreads();   // #2: gsum complete; also fences h_lds reuse

        // ---- wave 0: activations, state update, publish ----
        if (wv == 0) {
            double actv = 0.0;
            if (ln < 32) {
                const int g = ln >> 3, j = ln & 7;
                double v = gsum[g][j] + bias_s[g][j];
                actv = (g == 2) ? tanh(v) : 1.0 / (1.0 + exp(-v));
            }
            const int j = ln & 7;
            double ai = __shfl(actv, j,      64);
            double af = __shfl(actv, j + 8,  64);
            double ag = __shfl(actv, j + 16, 64);
            double ao = __shfl(actv, j + 24, 64);
            if (ln < 8) {
                double c = af * c_reg + ai * ag;
                c_reg = c;
                float hnew = (float)(ao * tanh(c));
                u64* prec = recs + (((size_t)((t + 1) & rot_mask) * NBLK + b) << 3);
                u64 pv = ((u64)(unsigned)(t + 1) << 32)
                       | (u64)__builtin_bit_cast(unsigned, hnew);
                // single self-validating 8B store; no fence, no tag ordering
                __hip_atomic_store(prec + ln, pv, __ATOMIC_RELAXED,
                                   __HIP_MEMORY_SCOPE_AGENT);
            }
        }
        xr = xn;
    }

    // ---- epilogue: block 0 gathers h(SEQ) (slot SEQ&mask, tag SEQ) ----
    if (b == 0) {
        const u64* rec = recs + (((size_t)(SEQ & rot_mask) * NBLK + tid) << 3);
        double a0 = 0., a1 = 0.;
        #pragma unroll
        for (int e = 0; e < 8; ++e) {
            u64 v = __hip_atomic_load(rec + e, __ATOMIC_RELAXED,
                                      __HIP_MEMORY_SCOPE_AGENT);
            while ((unsigned)(v >> 32) != (unsigned)SEQ) {
                __builtin_amdgcn_s_sleep(4);
                v = __hip_atomic_load(rec + e, __ATOMIC_RELAXED,
                                      __HIP_MEMORY_SCOPE_AGENT);
            }
            double hv = (double)__builtin_bit_cast(float, (unsigned)v);
            a0 = fma((double)w_lin[8 * tid + e],     hv, a0);
            a1 = fma((double)w_lin[H + 8 * tid + e], hv, a1);
        }
        #pragma unroll
        for (int off = 32; off >= 1; off >>= 1) {
            a0 += __shfl_xor(a0, off, 64);
            a1 += __shfl_xor(a1, off, 64);
        }
        if (ln == 0) { red0[wv] = a0; red1[wv] = a1; }
        __syncthreads();
        if (tid == 0) {
            out[0] = (float)(red0[0] + red0[1] + red0[2] + red0[3] + (double)b_lin[0]);
            out[1] = (float)(red1[0] + red1[1] + red1[2] + red1[3] + (double)b_lin[1]);
        }
    }
}

extern "C" void kernel_launch(void* const* d_in, const int* in_sizes, int n_in,
                              void* d_out, int out_size, void* d_ws, size_t ws_size,
                              hipStream_t stream) {
    const float* x     = (const float*)d_in[0];
    const float* h0    = (const float*)d_in[1];
    const float* c0    = (const float*)d_in[2];
    const float* w_ih  = (const float*)d_in[3];
    const float* w_hh  = (const float*)d_in[4];
    const float* b_ih  = (const float*)d_in[5];
    const float* b_hh  = (const float*)d_in[6];
    const float* w_lin = (const float*)d_in[7];
    const float* b_lin = (const float*)d_in[8];
    float* out = (float*)d_out;
    u64*   recs = (u64*)d_ws;

    // rotation depth: largest power of two of 16KB slots fitting ws, <= 256
    const size_t slot_bytes = (size_t)NBLK * 8 * sizeof(u64);
    int rot = 2;
    while (rot < 256 && (size_t)(rot * 2) * slot_bytes <= ws_size) rot *= 2;
    const int rot_mask = rot - 1;

    lstm_init<<<1, NTHR, 0, stream>>>(h0, recs);
    lstm_persist<<<NBLK, NTHR, 0, stream>>>(
        x, c0, w_ih, w_hh, b_ih, b_hh, w_lin, b_lin, out, recs, rot_mask);
}

// Round 8
// 191392.041 us; speedup vs baseline: 1.0285x; 1.0285x over previous
//
#include <hip/hip_runtime.h>
#include <math.h>

#define SEQ   8192
#define NIN   256
#define H     2048
#define NBLK  256
#define NTHR  256

typedef unsigned long long u64;

// ---- ws layout ----
// 0     : float hA[2][H]          (16 KB) fp32 h transport, ping-pong
// 16384 : unsigned tags[2][NBLK]  (2 KB)  tag[slot][b] = step of record
__global__ void lstm_init(const float* __restrict__ h0, float* __restrict__ ws)
{
    const int j = threadIdx.x;   // one block of 256
    unsigned* tags = (unsigned*)(ws + 2 * H);
    #pragma unroll
    for (int r = 0; r < 8; ++r) ws[8 * j + r] = h0[8 * j + r];
    tags[j]        = 0u;           // slot 0 carries h_0 with tag 0
    tags[NBLK + j] = 0xFFFFFFFFu;  // slot 1 not ready
}

// Two agent-scope (sc1) 16B loads, wave-coalescable, then drain.
// (float4 OUTPUT constraints compile; 128-bit inputs do not — stores stay 4B.)
__device__ __forceinline__ void load2_f4_sc1(const float* p0, const float* p1,
                                             float4& a, float4& b)
{
    asm volatile(
        "global_load_dwordx4 %0, %2, off sc1\n\t"
        "global_load_dwordx4 %1, %3, off sc1\n\t"
        "s_waitcnt vmcnt(0)"
        : "=&v"(a), "=&v"(b)
        : "v"(p0), "v"(p1)
        : "memory");
}

// Wave-0-only tag poll: lane ln checks packed pairs (2 u64 = 4 tags) until
// all 256 tags of the slot == t. Relaxed sc1 atomics — no cache maintenance.
__device__ __forceinline__ void wave_poll_tags(const u64* tp, unsigned t, int ln)
{
    const u64 want = ((u64)t << 32) | (u64)t;
    for (;;) {
        u64 a = __hip_atomic_load(tp + ln,      __ATOMIC_RELAXED, __HIP_MEMORY_SCOPE_AGENT);
        u64 b = __hip_atomic_load(tp + 64 + ln, __ATOMIC_RELAXED, __HIP_MEMORY_SCOPE_AGENT);
        if (__all((a == want) && (b == want))) break;
        __builtin_amdgcn_s_sleep(1);
    }
}

// Persistent LSTM. fp32 weights register-resident, fp64 recurrence math,
// fp32 h transport. Block b owns h[8b..8b+8); wave wv computes gate wv.
// Lane ln holds w_hh[R][32ln..32ln+32) for its 8 rows.
__global__ void __launch_bounds__(NTHR, 1)
lstm_persist(const float* __restrict__ x, const float* __restrict__ c0,
             const float* __restrict__ w_ih, const float* __restrict__ w_hh,
             const float* __restrict__ b_ih, const float* __restrict__ b_hh,
             const float* __restrict__ w_lin, const float* __restrict__ b_lin,
             float* __restrict__ out, float* __restrict__ ws)
{
    const int b = blockIdx.x, tid = threadIdx.x;
    const int wv = tid >> 6, ln = tid & 63;
    float*     hA    = ws;
    unsigned*  tags  = (unsigned*)(ws + 2 * H);
    const u64* tagsU = (const u64*)tags;

    __shared__ float  h_lds[H + H / 32];   // stride-33: 2-way bank alias = free
    __shared__ double gsum[4][8];
    __shared__ double bias_s[4][8];
    __shared__ double red0[4], red1[4];

    if (tid < 32) {
        int g = tid >> 3, r = tid & 7;
        int R = g * H + b * 8 + r;
        bias_s[g][r] = (double)b_ih[R] + (double)b_hh[R];
    }
    double c_reg = (wv == 0 && ln < 8) ? (double)c0[b * 8 + ln] : 0.0;

    float wreg[8][32];
    float wih[8][4];
    #pragma unroll
    for (int r = 0; r < 8; ++r) {
        const int R = wv * H + b * 8 + r;
        const float4* wp = (const float4*)(w_hh + (size_t)R * H + ln * 32);
        #pragma unroll
        for (int q = 0; q < 8; ++q) ((float4*)wreg[r])[q] = wp[q];
        *(float4*)wih[r] = *(const float4*)(w_ih + (size_t)R * NIN + ln * 4);
    }
    __syncthreads();

    float4 xr = *(const float4*)(x + ln * 4);
    float4 xn = xr;

    for (int t = 0; t < SEQ; ++t) {
        const int slot = t & 1;

        if (wv == 0) wave_poll_tags(tagsU + slot * (NBLK / 2), (unsigned)t, ln);
        __syncthreads();   // #1: all 256 records of step t committed

        // ---- consume: coalesced wide sc1 reads of the 8 KB image ----
        {
            const float* img = hA + slot * H;
            float4 va, vb;
            load2_f4_sc1(img + 4 * tid, img + 1024 + 4 * tid, va, vb);
            const int b0 = 4 * tid + (tid >> 3);            // pad: +1 per 32
            h_lds[b0 + 0] = va.x; h_lds[b0 + 1] = va.y;
            h_lds[b0 + 2] = va.z; h_lds[b0 + 3] = va.w;
            const int b1 = 1056 + 4 * tid + (tid >> 3);     // (1024+4t)+pad
            h_lds[b1 + 0] = vb.x; h_lds[b1 + 1] = vb.y;
            h_lds[b1 + 2] = vb.z; h_lds[b1 + 3] = vb.w;
        }
        __syncthreads();   // #2: full h of step t in LDS

        if (t + 1 < SEQ) xn = *(const float4*)(x + (size_t)(t + 1) * NIN + ln * 4);

        // ---- matvec: fp32 w x fp32 h, fp64 accumulate ----
        float hbuf[32];
        {
            const float* hp = &h_lds[33 * ln];
            #pragma unroll
            for (int q = 0; q < 32; ++q) hbuf[q] = hp[q];
        }
        double acc[8];
        #pragma unroll
        for (int r = 0; r < 8; ++r)
            acc[r] = (double)wih[r][0] * (double)xr.x + (double)wih[r][1] * (double)xr.y
                   + (double)wih[r][2] * (double)xr.z + (double)wih[r][3] * (double)xr.w;
        #pragma unroll
        for (int q = 0; q < 32; ++q) {
            const double hq = (double)hbuf[q];
            #pragma unroll
            for (int r = 0; r < 8; ++r)
                acc[r] = fma((double)wreg[r][q], hq, acc[r]);
        }
        #pragma unroll
        for (int off = 32; off >= 1; off >>= 1) {
            #pragma unroll
            for (int r = 0; r < 8; ++r) acc[r] += __shfl_xor(acc[r], off, 64);
        }
        if (ln == 0) {
            #pragma unroll
            for (int r = 0; r < 8; ++r) gsum[wv][r] = acc[r];
        }
        __syncthreads();   // #3: gsum complete

        // ---- wave 0: activations, state update, publish (8 x 4B, one line) ----
        if (wv == 0) {
            double actv = 0.0;
            if (ln < 32) {
                const int g = ln >> 3, j = ln & 7;
                double v = gsum[g][j] + bias_s[g][j];
                actv = (g == 2) ? tanh(v) : 1.0 / (1.0 + exp(-v));
            }
            const int j = ln & 7;
            double ai = __shfl(actv, j,      64);
            double af = __shfl(actv, j + 8,  64);
            double ag = __shfl(actv, j + 16, 64);
            double ao = __shfl(actv, j + 24, 64);
            if (ln < 8) {
                double c = af * c_reg + ai * ag;
                c_reg = c;
                float hnew = (float)(ao * tanh(c));
                unsigned* dst = (unsigned*)(hA + (1 - slot) * H) + 8 * b + ln;
                __hip_atomic_store(dst, __builtin_bit_cast(unsigned, hnew),
                                   __ATOMIC_RELAXED, __HIP_MEMORY_SCOPE_AGENT);
            }
            asm volatile("s_waitcnt vmcnt(0)" ::: "memory");
            if (ln == 0)
                __hip_atomic_store(&tags[(1 - slot) * NBLK + b], (unsigned)(t + 1),
                                   __ATOMIC_RELAXED, __HIP_MEMORY_SCOPE_AGENT);
        }
        xr = xn;
    }

    // ---- epilogue: block 0 gathers h(SEQ) (slot 0, tag SEQ) ----
    if (b == 0) {
        if (wv == 0) wave_poll_tags(tagsU, (unsigned)SEQ, ln);
        __syncthreads();
        float4 va, vb;
        load2_f4_sc1(hA + 4 * tid, hA + 1024 + 4 * tid, va, vb);
        double a0 = 0., a1 = 0.;
        const float* w0 = w_lin;
        const float* w1 = w_lin + H;
        const int k0 = 4 * tid, k1 = 1024 + 4 * tid;
        a0 = fma((double)w0[k0],     (double)va.x, a0);
        a0 = fma((double)w0[k0 + 1], (double)va.y, a0);
        a0 = fma((double)w0[k0 + 2], (double)va.z, a0);
        a0 = fma((double)w0[k0 + 3], (double)va.w, a0);
        a0 = fma((double)w0[k1],     (double)vb.x, a0);
        a0 = fma((double)w0[k1 + 1], (double)vb.y, a0);
        a0 = fma((double)w0[k1 + 2], (double)vb.z, a0);
        a0 = fma((double)w0[k1 + 3], (double)vb.w, a0);
        a1 = fma((double)w1[k0],     (double)va.x, a1);
        a1 = fma((double)w1[k0 + 1], (double)va.y, a1);
        a1 = fma((double)w1[k0 + 2], (double)va.z, a1);
        a1 = fma((double)w1[k0 + 3], (double)va.w, a1);
        a1 = fma((double)w1[k1],     (double)vb.x, a1);
        a1 = fma((double)w1[k1 + 1], (double)vb.y, a1);
        a1 = fma((double)w1[k1 + 2], (double)vb.z, a1);
        a1 = fma((double)w1[k1 + 3], (double)vb.w, a1);
        #pragma unroll
        for (int off = 32; off >= 1; off >>= 1) {
            a0 += __shfl_xor(a0, off, 64);
            a1 += __shfl_xor(a1, off, 64);
        }
        if (ln == 0) { red0[wv] = a0; red1[wv] = a1; }
        __syncthreads();
        if (tid == 0) {
            out[0] = (float)(red0[0] + red0[1] + red0[2] + red0[3] + (double)b_lin[0]);
            out[1] = (float)(red1[0] + red1[1] + red1[2] + red1[3] + (double)b_lin[1]);
        }
    }
}

extern "C" void kernel_launch(void* const* d_in, const int* in_sizes, int n_in,
                              void* d_out, int out_size, void* d_ws, size_t ws_size,
                              hipStream_t stream) {
    const float* x     = (const float*)d_in[0];
    const float* h0    = (const float*)d_in[1];
    const float* c0    = (const float*)d_in[2];
    const float* w_ih  = (const float*)d_in[3];
    const float* w_hh  = (const float*)d_in[4];
    const float* b_ih  = (const float*)d_in[5];
    const float* b_hh  = (const float*)d_in[6];
    const float* w_lin = (const float*)d_in[7];
    const float* b_lin = (const float*)d_in[8];
    float* out = (float*)d_out;
    float* ws  = (float*)d_ws;

    lstm_init<<<1, NTHR, 0, stream>>>(h0, ws);
    lstm_persist<<<NBLK, NTHR, 0, stream>>>(
        x, c0, w_ih, w_hh, b_ih, b_hh, w_lin, b_lin, out, ws);
}